// Round 11
// baseline (4877.705 us; speedup 1.0000x reference)
//
#include <hip/hip_runtime.h>

// Problem constants
#define BB 128
#define TT 512
#define HH 512
#define K4H 2048
#define KTOT 1024   // combined K: k<512 -> h@Wh, k>=512 -> x@Wx

typedef short bfrag  __attribute__((ext_vector_type(8)));   // 8 bf16 (4 VGPRs)
typedef float facc   __attribute__((ext_vector_type(16)));  // 16 f32 acc
typedef unsigned short u16;
typedef unsigned short ushortx8 __attribute__((ext_vector_type(8)));
typedef unsigned long long u64;
typedef u64 u64x2 __attribute__((ext_vector_type(2)));
typedef unsigned int u32;

__device__ __forceinline__ u16 f2bf(float x){
    unsigned u = __builtin_bit_cast(unsigned, x);
    unsigned r = (u + 0x7fffu + ((u >> 16) & 1u)) >> 16;   // RNE
    return (u16)r;
}
__device__ __forceinline__ float bf2f(u16 h){
    unsigned u = ((unsigned)h) << 16;
    return __builtin_bit_cast(float, u);
}
__device__ __forceinline__ float fast_tanh(float x){
    float e = __expf(2.f * x);
    return 1.f - 2.f * __builtin_amdgcn_rcpf(e + 1.f);
}
__device__ __forceinline__ float fast_sig(float x){
    return __builtin_amdgcn_rcpf(1.f + __expf(-x));
}
__device__ __forceinline__ bfrag mkfrag(u64 a, u64 b){
    u64x2 v; v.x = a; v.y = b;
    return __builtin_bit_cast(bfrag, v);
}

// ---- prep: X -> bf16 hi/lo split ----
__global__ void prep_x(const float* __restrict__ X, u16* __restrict__ Xhi, u16* __restrict__ Xlo){
    size_t g = (size_t)blockIdx.x * blockDim.x + threadIdx.x;   // one float4 per thread
    float4 v = ((const float4*)X)[g];
    u16 h0 = f2bf(v.x), h1 = f2bf(v.y), h2 = f2bf(v.z), h3 = f2bf(v.w);
    ushort4 hh; hh.x = h0; hh.y = h1; hh.z = h2; hh.w = h3;
    ushort4 ll;
    ll.x = f2bf(v.x - bf2f(h0)); ll.y = f2bf(v.y - bf2f(h1));
    ll.z = f2bf(v.z - bf2f(h2)); ll.w = f2bf(v.w - bf2f(h3));
    ((ushort4*)Xhi)[g] = hh;
    ((ushort4*)Xlo)[g] = ll;
}

// ---- prep: transpose+split weights into WT[c][k], k = [Wh rows | Wx rows] ----
__global__ void prep_w(const float* __restrict__ Wx, const float* __restrict__ Wh,
                       u16* __restrict__ WThi, u16* __restrict__ WTlo){
    int c = blockIdx.x;  // 0..2047
    for (int kk = threadIdx.x; kk < KTOT; kk += blockDim.x){
        float w = (kk < 512) ? Wh[(size_t)kk * K4H + c] : Wx[(size_t)(kk - 512) * K4H + c];
        u16 hi = f2bf(w);
        u16 lo = f2bf(w - bf2f(hi));
        WThi[(size_t)c * KTOT + kk] = hi;
        WTlo[(size_t)c * KTOT + kk] = lo;
    }
}

// ---- prep: h buffers with parity tags, slots (unused), out row t=0 ----
// Tag: LSB of every stored bf16 (hi AND lo) = ((step)>>1)&1 of the h living there.
// buf0 = h_0 = zeros, tag 0 (t=0 expects parity 0 -> passes immediately).
// buf1 poisoned tag 1 (t=1 expects parity 0 -> consumers wait for real h_1).
__global__ void prep_misc(u16* __restrict__ hH, u16* __restrict__ hL,
                          u32* __restrict__ cbar, float* __restrict__ out){
    int i = blockIdx.x * blockDim.x + threadIdx.x;   // 131072 threads (full dbuf)
    u16 ini = (i < 65536) ? (u16)0 : (u16)1;
    hH[i] = ini; hL[i] = ini;
    if (i < 256) cbar[i] = 0;
    if (i < 65536){
        int b = i >> 9, j = i & 511;
        out[(size_t)b * (TT * HH) + j] = 0.f;        // out[b][0][j]
    }
}

// 3-product split-bf16 MFMA (hi*hi + hi*lo + lo*hi)
#define MF3(ACC, AH, AL, BH, BL) \
    ACC = __builtin_amdgcn_mfma_f32_32x32x16_bf16(AH, BH, ACC, 0, 0, 0); \
    ACC = __builtin_amdgcn_mfma_f32_32x32x16_bf16(AH, BL, ACC, 0, 0, 0); \
    ACC = __builtin_amdgcn_mfma_f32_32x32x16_bf16(AL, BH, ACC, 0, 0, 0);

// ---- main cooperative kernel: 256 WGs x 256 thr (verified geometry), 511 steps ----
// v11 = verified v10 (4690 us) with ONE change: h acquired in HALVES (2 x 16 u64)
// instead of quarters (4 x 8 u64). The retry loop's unknown trip count pins atomic
// loads in program order, so quarters serialized 4 full IC round-trips on the fast
// path; halves make it 2 (12 MFMAs amortize each). Transient regs +16 VGPR (~140
// class; all verified passes <=124, mystery launch failures >=~200 demand --
// full 32-u64 upfront staging would be ~170+ and risks spill, so take the half-step).
// All v10 semantics preserved: self-validating parity-tagged h, agent-scope u64
// loads (no fences anywhere), WAR-safe by the full-k-coverage argument, sync (C)
// for red visibility, sync (D) for the red WAR across steps.
__global__ void __launch_bounds__(256, 1) lstm_main(
    const u16* __restrict__ Xhi, const u16* __restrict__ Xlo,
    const u16* __restrict__ WThi, const u16* __restrict__ WTlo,
    const float* __restrict__ bias,
    u16* __restrict__ hH, u16* __restrict__ hL,
    u32* __restrict__ cbar,
    float* __restrict__ out)
{
    __shared__ float red[4][32][36];   // pitch 36: <=2-way bank aliasing

    const int tid  = threadIdx.x;
    const int lane = tid & 63;
    const int kh   = tid >> 6;         // wave id = K-split index
    const int wid  = blockIdx.x;
    const int bt   = wid & 3;          // batch tile (32 batches)
    const int js   = wid >> 2;         // j-set (8 h-indices)

    const int n  = lane & 31;          // MFMA row/col within tile
    const int kg = (lane >> 5) * 8;    // k sub-group

    // B fragments: named scalars -> register-resident for all 511 steps
    const int c_n = (n >> 3) * 512 + js * 8 + (n & 7);   // global column for frag col n
    const size_t wrow = (size_t)c_n * KTOT;

#define LDB(NH, NL, KK) \
    bfrag NH = __builtin_bit_cast(bfrag, *(const ushortx8*)(WThi + wrow + (KK))); \
    bfrag NL = __builtin_bit_cast(bfrag, *(const ushortx8*)(WTlo + wrow + (KK)));

    LDB(bh0, bl0, kh*128 + 0*16 + kg)      // h-part weights
    LDB(bh1, bl1, kh*128 + 1*16 + kg)
    LDB(bh2, bl2, kh*128 + 2*16 + kg)
    LDB(bh3, bl3, kh*128 + 3*16 + kg)
    LDB(bh4, bl4, kh*128 + 4*16 + kg)
    LDB(bh5, bl5, kh*128 + 5*16 + kg)
    LDB(bh6, bl6, kh*128 + 6*16 + kg)
    LDB(bh7, bl7, kh*128 + 7*16 + kg)
    LDB(cx0, dx0, 512 + kh*128 + 0*16 + kg)  // x-part weights
    LDB(cx1, dx1, 512 + kh*128 + 1*16 + kg)
    LDB(cx2, dx2, 512 + kh*128 + 2*16 + kg)
    LDB(cx3, dx3, 512 + kh*128 + 3*16 + kg)
    LDB(cx4, dx4, 512 + kh*128 + 4*16 + kg)
    LDB(cx5, dx5, 512 + kh*128 + 5*16 + kg)
    LDB(cx6, dx6, 512 + kh*128 + 6*16 + kg)
    LDB(cx7, dx7, 512 + kh*128 + 7*16 + kg)

    // A-fragment addressing (row m = n lane field)
    const int bgm = bt * 32 + n;                        // global batch row for A
    const size_t xrow = (size_t)bgm * (TT * 512);       // + t*512 + k
    const int xk    = kh * 128 + kg;
    const int hbase = bgm * 512 + kh * 128 + kg;

    // gate threads: tid<128, each owns (batch, 2 adjacent j) so h stores are u32s
    const int blt = tid >> 2;            // 0..31 batch local (tid<128)
    const int jp  = (tid & 3) * 2;       // 0,2,4,6
    const int bg  = bt * 32 + blt;
    const int jg0 = js * 8 + jp;
    float biasr[8];
    if (tid < 128){
#pragma unroll
        for (int g = 0; g < 4; g++){
            biasr[2*g]   = bias[g * 512 + jg0];
            biasr[2*g+1] = bias[g * 512 + jg0 + 1];
        }
    }

    float cs0 = 0.f, cs1 = 0.f;
    facc acc0 = {0.f,0.f,0.f,0.f,0.f,0.f,0.f,0.f,0.f,0.f,0.f,0.f,0.f,0.f,0.f,0.f};
    facc acc1 = {0.f,0.f,0.f,0.f,0.f,0.f,0.f,0.f,0.f,0.f,0.f,0.f,0.f,0.f,0.f,0.f};

#define XSTEP(I, ACC, BH, BL) do{ \
    bfrag ah = __builtin_bit_cast(bfrag, *(const ushortx8*)(xh + I*16)); \
    bfrag al = __builtin_bit_cast(bfrag, *(const ushortx8*)(xl + I*16)); \
    MF3(ACC, ah, al, BH, BL) }while(0)

#define LDA(P) __hip_atomic_load((const u64*)(P), __ATOMIC_RELAXED, __HIP_MEMORY_SCOPE_AGENT)

    const u64 TAGM = 0x0001000100010001ull;

// Half H = chunks 4H..4H+3 (16 u64 in flight). Retry until all 16 values carry the
// expected parity tag; consume straight into 12 MFMAs. Half 0's retry is the wait.
#define HHALF(H, BHa, BLa, BHb, BLb, BHc, BLc, BHd, BLd) do{ \
    const u64* p0h = (const u64*)(hhp + (4*(H)+0)*16); \
    const u64* p1h = (const u64*)(hhp + (4*(H)+1)*16); \
    const u64* p2h = (const u64*)(hhp + (4*(H)+2)*16); \
    const u64* p3h = (const u64*)(hhp + (4*(H)+3)*16); \
    const u64* p0l = (const u64*)(hlp + (4*(H)+0)*16); \
    const u64* p1l = (const u64*)(hlp + (4*(H)+1)*16); \
    const u64* p2l = (const u64*)(hlp + (4*(H)+2)*16); \
    const u64* p3l = (const u64*)(hlp + (4*(H)+3)*16); \
    u64 a0,a1,a2,a3,a4,a5,a6,a7,b0,b1,b2,b3,b4,b5,b6,b7; \
    for(;;){ \
        a0 = LDA(p0h); a1 = LDA(p0h+1); a2 = LDA(p1h); a3 = LDA(p1h+1); \
        a4 = LDA(p2h); a5 = LDA(p2h+1); a6 = LDA(p3h); a7 = LDA(p3h+1); \
        b0 = LDA(p0l); b1 = LDA(p0l+1); b2 = LDA(p1l); b3 = LDA(p1l+1); \
        b4 = LDA(p2l); b5 = LDA(p2l+1); b6 = LDA(p3l); b7 = LDA(p3l+1); \
        u64 m = (a0^par)|(a1^par)|(a2^par)|(a3^par) \
              | (a4^par)|(a5^par)|(a6^par)|(a7^par) \
              | (b0^par)|(b1^par)|(b2^par)|(b3^par) \
              | (b4^par)|(b5^par)|(b6^par)|(b7^par); \
        if (__all((int)((m & TAGM) == 0ull))) break; \
        __builtin_amdgcn_s_sleep(1); \
    } \
    MF3(acc0, mkfrag(a0,a1), mkfrag(b0,b1), BHa, BLa) \
    MF3(acc1, mkfrag(a2,a3), mkfrag(b2,b3), BHb, BLb) \
    MF3(acc0, mkfrag(a4,a5), mkfrag(b4,b5), BHc, BLc) \
    MF3(acc1, mkfrag(a6,a7), mkfrag(b6,b7), BHd, BLd) }while(0)

    for (int t = 0; t < 511; t++){
        // ---- x-part GEMM (independent of h; L2-cached -- no fences exist) ----
        const u16* xh = Xhi + xrow + (size_t)t * 512 + xk;
        const u16* xl = Xlo + xrow + (size_t)t * 512 + xk;
        XSTEP(0, acc0, cx0, dx0);
        XSTEP(1, acc1, cx1, dx1);
        XSTEP(2, acc0, cx2, dx2);
        XSTEP(3, acc1, cx3, dx3);
        XSTEP(4, acc0, cx4, dx4);
        XSTEP(5, acc1, cx5, dx5);
        XSTEP(6, acc0, cx6, dx6);
        XSTEP(7, acc1, cx7, dx7);

        // ---- tag-validated h acquisition + h-GEMM: 2 IC round-trips fast-path ----
        const u16* hhp = hH + (size_t)(t & 1) * (BB * 512) + hbase;
        const u16* hlp = hL + (size_t)(t & 1) * (BB * 512) + hbase;
        const u64 par = ((t >> 1) & 1) ? TAGM : 0ull;
        HHALF(0, bh0, bl0, bh1, bl1, bh2, bl2, bh3, bl3);
        HHALF(1, bh4, bl4, bh5, bl5, bh6, bl6, bh7, bl7);

        // ---- split-K reduction via LDS ----
#pragma unroll
        for (int r = 0; r < 16; r++){
            int mrow = (r & 3) + 8 * (r >> 2) + 4 * (lane >> 5);  // verified C layout
            red[kh][mrow][n] = acc0[r] + acc1[r];
        }
#pragma unroll
        for (int r = 0; r < 16; r++){ acc0[r] = 0.f; acc1[r] = 0.f; }
        __syncthreads();   // (C) red visible to gates; also anchors the WAR proof

        // ---- gates + state update + tagged publish: tid<128 ----
        if (tid < 128){
            float v0[4], v1[4];
#pragma unroll
            for (int g = 0; g < 4; g++){
                int nn = g * 8 + jp;
                v0[g] = red[0][blt][nn]   + red[1][blt][nn]   + red[2][blt][nn]   + red[3][blt][nn]   + biasr[2*g];
                v1[g] = red[0][blt][nn+1] + red[1][blt][nn+1] + red[2][blt][nn+1] + red[3][blt][nn+1] + biasr[2*g+1];
            }
            float f0 = fast_sig(fast_tanh(v0[0])), f1 = fast_sig(fast_tanh(v1[0]));
            float g0 = fast_tanh(fast_tanh(v0[1])), g1 = fast_tanh(fast_tanh(v1[1]));
            float i0 = fast_sig(fast_tanh(v0[2])), i1 = fast_sig(fast_tanh(v1[2]));
            float o0 = fast_sig(fast_tanh(v0[3])), o1 = fast_sig(fast_tanh(v1[3]));
            float hn0 = o0 * fast_tanh(cs0);
            float hn1 = o1 * fast_tanh(cs1);
            cs0 = f0 * cs0 + g0 * i0;
            cs1 = f1 * cs1 + g1 * i1;

            // h hi/lo with parity tag in every bf16 LSB; lo absorbs hi's forced LSB
            // (residual ~2^-16 relative -- far under the absmax margin).
            u16 pb = (u16)(((t + 1) >> 1) & 1);
            u16 h0i = (u16)((f2bf(hn0) & 0xFFFEu) | pb);
            u16 h1i = (u16)((f2bf(hn1) & 0xFFFEu) | pb);
            u32 hpack = (u32)h0i | ((u32)h1i << 16);
            u16 l0i = (u16)((f2bf(hn0 - bf2f(h0i)) & 0xFFFEu) | pb);
            u16 l1i = (u16)((f2bf(hn1 - bf2f(h1i)) & 0xFFFEu) | pb);
            u32 lpack = (u32)l0i | ((u32)l1i << 16);
            size_t hidx = (size_t)((t + 1) & 1) * (BB * 512) + (size_t)bg * 512 + jg0;
            __hip_atomic_store((u32*)(hH + hidx), hpack, __ATOMIC_RELAXED, __HIP_MEMORY_SCOPE_AGENT);
            __hip_atomic_store((u32*)(hL + hidx), lpack, __ATOMIC_RELAXED, __HIP_MEMORY_SCOPE_AGENT);

            // out: after the h publish (off the recurrence path; drains at endpgm)
            float2 ov; ov.x = hn0; ov.y = hn1;
            u64 opack = __builtin_bit_cast(u64, ov);
            __hip_atomic_store((u64*)(out + (size_t)bg * (TT * HH) + (size_t)(t + 1) * HH + jg0),
                               opack, __ATOMIC_RELAXED, __HIP_MEMORY_SCOPE_AGENT);
        }

        __syncthreads();   // (D) LDS `red` WAR: no wave starts next reduce early
    }
}

extern "C" void kernel_launch(void* const* d_in, const int* in_sizes, int n_in,
                              void* d_out, int out_size, void* d_ws, size_t ws_size,
                              hipStream_t stream)
{
    const float* X    = (const float*)d_in[0];
    const float* Wx   = (const float*)d_in[1];
    const float* Wh   = (const float*)d_in[2];
    const float* bias = (const float*)d_in[3];
    float* out = (float*)d_out;

    char* ws = (char*)d_ws;
    u16* Xhi  = (u16*)(ws);                      // 64 MiB
    u16* Xlo  = (u16*)(ws + 67108864ull);        // 64 MiB
    u16* WThi = (u16*)(ws + 134217728ull);       // 4 MiB
    u16* WTlo = (u16*)(ws + 138412032ull);       // 4 MiB
    u16* hHp  = (u16*)(ws + 142606336ull);       // 256 KiB (double buffered)
    u16* hLp  = (u16*)(ws + 142868480ull);       // 256 KiB
    u32* cbar = (u32*)(ws + 143130624ull);       // 1 KiB (unused by v11, kept)

    hipLaunchKernelGGL(prep_x,    dim3(32768), dim3(256), 0, stream, X, Xhi, Xlo);
    hipLaunchKernelGGL(prep_w,    dim3(2048),  dim3(256), 0, stream, Wx, Wh, WThi, WTlo);
    hipLaunchKernelGGL(prep_misc, dim3(512),   dim3(256), 0, stream, hHp, hLp, cbar, out);

    void* args[] = { (void*)&Xhi, (void*)&Xlo, (void*)&WThi, (void*)&WTlo,
                     (void*)&bias, (void*)&hHp, (void*)&hLp, (void*)&cbar, (void*)&out };
    hipLaunchCooperativeKernel(lstm_main, dim3(256), dim3(256), args, 0, stream);
}